// Round 1
// baseline (416.174 us; speedup 1.0000x reference)
//
#include <hip/hip_runtime.h>

#define NUMC 14
#define FD 128
#define SPATIAL (16*128*128)      // 262144 per batch
#define N_TOTAL (2*SPATIAL)       // 524288
#define NV 50
#define NH 25
#define TC 13
#define QLEN 4096
#define MCH 64                    // negatives per k_neg block
#define NCHUNK 32                 // 2048 / MCH
#define CHUNK 1024
#define NBLK2 (N_TOTAL / CHUNK)   // 512
#define THRESH_F 0.3f

// ws offsets in 4-byte units
#define WS_SEL     0              // int[656]
#define WS_ANORM   656            // float[656]
#define WS_CNTS    1312           // float[16]
#define WS_SUMS    1328           // float[14*128]
#define WS_NEGPART 3120           // float[32*650]
#define WS_AROWS   23920          // float[650*128]
#define WS_PART    107120         // float[512*1792]
#define WS_CNTPART 1024624        // float[512*16]

__global__ void k_select(const int* __restrict__ labels, const int* __restrict__ predict,
                         const float* __restrict__ prob, int* __restrict__ sel) {
    int cat = blockIdx.x;              // 0..25
    int c = 1 + (cat >> 1);
    bool hard = (cat & 1) == 0;
    int lane = threadIdx.x;            // 0..63
    int* slot = sel + (c - 1) * NV + (hard ? 0 : NH);
    int found = 0;
    for (int base = 0; base < N_TOTAL && found < NH; base += 64) {
        int n = base + lane;
        bool m = false;
        if (n < N_TOTAL) {
            int pr = predict[n];
            if (pr == c && prob[n] > THRESH_F) {
                int lb = labels[n];
                m = hard ? (lb != c) : (lb == c);
            }
        }
        unsigned long long mask = __ballot(m);
        int rank = __popcll(mask & ((1ull << lane) - 1ull));
        if (m && (found + rank) < NH) slot[found + rank] = n;
        found += __popcll(mask);
    }
    if (lane >= found && lane < NH) slot[lane] = N_TOTAL - 1;  // clamp semantics of OOB gather
}

__global__ __launch_bounds__(256) void k_partial(const float* __restrict__ feats,
        const int* __restrict__ labels, const float* __restrict__ prob,
        float* __restrict__ part, float* __restrict__ cntpart) {
    __shared__ int   lab_s[CHUNK];
    __shared__ float sums_s[NUMC * 129];
    __shared__ float cnt_s[16];
    int tid = threadIdx.x;
    int base = blockIdx.x * CHUNK;
    for (int i = tid; i < NUMC * 129; i += 256) sums_s[i] = 0.f;
    if (tid < 16) cnt_s[tid] = 0.f;
    __syncthreads();
    {
        int n = base + tid * 4;
        int4   lb = *(const int4*)(labels + n);
        float4 pv = *(const float4*)(prob + n);
        int l0 = pv.x > THRESH_F ? lb.x : -1;
        int l1 = pv.y > THRESH_F ? lb.y : -1;
        int l2 = pv.z > THRESH_F ? lb.z : -1;
        int l3 = pv.w > THRESH_F ? lb.w : -1;
        lab_s[tid*4+0] = l0; lab_s[tid*4+1] = l1;
        lab_s[tid*4+2] = l2; lab_s[tid*4+3] = l3;
        if (l0 >= 0) atomicAdd(&cnt_s[l0], 1.f);
        if (l1 >= 0) atomicAdd(&cnt_s[l1], 1.f);
        if (l2 >= 0) atomicAdd(&cnt_s[l2], 1.f);
        if (l3 >= 0) atomicAdd(&cnt_s[l3], 1.f);
    }
    __syncthreads();
    int b  = base / SPATIAL;
    int sp = base % SPATIAL;
    const float* fp = feats + (size_t)b * FD * SPATIAL + sp;
    int i0 = tid * 4;
    int l0 = lab_s[i0], l1 = lab_s[i0+1], l2 = lab_s[i0+2], l3 = lab_s[i0+3];
    #pragma unroll 4
    for (int c = 0; c < FD; ++c) {
        float4 v = ((const float4*)(fp + (size_t)c * SPATIAL))[tid];
        if (l0 >= 0) atomicAdd(&sums_s[l0*129 + c], v.x);
        if (l1 >= 0) atomicAdd(&sums_s[l1*129 + c], v.y);
        if (l2 >= 0) atomicAdd(&sums_s[l2*129 + c], v.z);
        if (l3 >= 0) atomicAdd(&sums_s[l3*129 + c], v.w);
    }
    __syncthreads();
    float* po = part + (size_t)blockIdx.x * (NUMC * FD);
    for (int i = tid; i < NUMC * FD; i += 256) po[i] = sums_s[(i >> 7) * 129 + (i & 127)];
    if (tid < 16) cntpart[blockIdx.x * 16 + tid] = cnt_s[tid];
}

__global__ __launch_bounds__(256) void k_reduce(const float* __restrict__ part,
        const float* __restrict__ cntpart, float* __restrict__ sums, float* __restrict__ cnts) {
    int idx = blockIdx.x * 256 + threadIdx.x;
    if (idx < NUMC * FD) {
        float s = 0.f;
        for (int b = 0; b < NBLK2; ++b) s += part[(size_t)b * (NUMC * FD) + idx];
        sums[idx] = s;
    } else if (idx < NUMC * FD + 16) {
        int j = idx - NUMC * FD;
        float s = 0.f;
        for (int b = 0; b < NBLK2; ++b) s += cntpart[b * 16 + j];
        cnts[j] = s;
    }
}

__global__ void k_gather(const float* __restrict__ feats, const int* __restrict__ sel,
                         float* __restrict__ arows, float* __restrict__ anorm) {
    int r = blockIdx.x;          // 0..649
    int lane = threadIdx.x;      // 0..63
    int n = sel[r];
    int b = n / SPATIAL, sp = n % SPATIAL;
    const float* fp = feats + (size_t)b * FD * SPATIAL + sp;
    float acc = 0.f;
    for (int k = lane; k < FD; k += 64) {
        float v = fp[(size_t)k * SPATIAL];
        arows[r * FD + k] = v;
        acc += v * v;
    }
    #pragma unroll
    for (int o = 32; o; o >>= 1) acc += __shfl_xor(acc, o);
    if (lane == 0) anorm[r] = sqrtf(acc);
}

__global__ __launch_bounds__(256) void k_neg(const float* __restrict__ queue,
        const float* __restrict__ arows, const float* __restrict__ anorm,
        float* __restrict__ negpart) {
    constexpr int NSTR = FD + 4;   // 132 floats: float4-aligned rows, banks spread
    __shared__ float a_s[NV * FD];
    __shared__ float n_s[MCH * NSTR];
    __shared__ float an_s[NV];
    int tid = threadIdx.x;
    int ci = blockIdx.x >> 5;      // 0..12
    int chunk = blockIdx.x & 31;   // 0..31
    const float* ap = arows + ci * (NV * FD);
    for (int i = tid; i < NV * FD / 4; i += 256) ((float4*)a_s)[i] = ((const float4*)ap)[i];
    if (tid < NV) an_s[tid] = anorm[ci * NV + tid];
    const float* qp = queue + ((size_t)(ci + 1) * QLEN + (QLEN / 2) + chunk * MCH) * (size_t)FD;
    for (int i = tid; i < MCH * FD / 4; i += 256) {
        int m = i / (FD / 4), k4 = i % (FD / 4);
        ((float4*)(n_s + m * NSTR))[k4] = ((const float4*)qp)[i];
    }
    __syncthreads();
    int lane = tid & 63, w = tid >> 6;
    // hoist this lane's negative row into registers; compute its norm in-reg
    float4 nr[FD / 4];
    const float4* nrow = (const float4*)(n_s + lane * NSTR);
    float sq = 0.f;
    #pragma unroll
    for (int k = 0; k < FD / 4; ++k) {
        nr[k] = nrow[k];
        sq += nr[k].x*nr[k].x + nr[k].y*nr[k].y + nr[k].z*nr[k].z + nr[k].w*nr[k].w;
    }
    float inn = 10.f / sqrtf(sq);   // 1/TEMP folded in
    float* np = negpart + chunk * (TC * NV) + ci * NV;
    for (int v = w; v < NV; v += 4) {
        const float4* a4 = (const float4*)(a_s + v * FD);  // wave-uniform -> LDS broadcast
        float dot = 0.f;
        #pragma unroll
        for (int k = 0; k < FD / 4; ++k) {
            float4 x = a4[k];
            dot += x.x*nr[k].x + x.y*nr[k].y + x.z*nr[k].z + x.w*nr[k].w;
        }
        float e = __expf(dot * inn / an_s[v]);
        #pragma unroll
        for (int o = 32; o; o >>= 1) e += __shfl_xor(e, o);
        if (lane == 0) np[v] = e;
    }
}

__global__ __launch_bounds__(256) void k_final(const float* __restrict__ arows,
        const float* __restrict__ anorm, const float* __restrict__ sums,
        const float* __restrict__ cnts, const float* __restrict__ negpart,
        float* __restrict__ out) {
    __shared__ float p_s[TC * FD];
    __shared__ float pn_s[TC];
    __shared__ float red[256];
    int tid = threadIdx.x;
    for (int i = tid; i < TC * FD; i += 256) {
        int c = i >> 7, k = i & 127;
        p_s[i] = sums[(c + 1) * FD + k] / cnts[c + 1];
    }
    __syncthreads();
    if (tid < TC) {
        float s = 0.f;
        for (int k = 0; k < FD; ++k) { float v = p_s[tid * FD + k]; s += v * v; }
        pn_s[tid] = sqrtf(s);
    }
    __syncthreads();
    float acc = 0.f;
    for (int r = tid; r < TC * NV; r += 256) {
        int c = r / NV;
        const float4* ar4 = (const float4*)(arows + r * FD);
        const float4* p4  = (const float4*)(p_s + c * FD);
        float dot = 0.f;
        #pragma unroll
        for (int k = 0; k < FD / 4; ++k) {
            float4 x = ar4[k], y = p4[k];
            dot += x.x*y.x + x.y*y.y + x.z*y.z + x.w*y.w;
        }
        float logit = dot / (anorm[r] * pn_s[c] * 0.1f);
        float ns = 0.f;
        for (int ch = 0; ch < NCHUNK; ++ch) ns += negpart[ch * (TC * NV) + r];
        acc += -logit + logf(__expf(logit) + ns);
    }
    red[tid] = acc;
    __syncthreads();
    for (int s = 128; s; s >>= 1) {
        if (tid < s) red[tid] += red[tid + s];
        __syncthreads();
    }
    if (tid == 0) out[0] = red[0] * (1.f / (TC * NV));
}

extern "C" void kernel_launch(void* const* d_in, const int* in_sizes, int n_in,
                              void* d_out, int out_size, void* d_ws, size_t ws_size,
                              hipStream_t stream) {
    (void)in_sizes; (void)n_in; (void)out_size; (void)ws_size;
    const float* feats   = (const float*)d_in[0];
    const int*   labels  = (const int*)d_in[1];
    const int*   predict = (const int*)d_in[2];
    const float* prob    = (const float*)d_in[3];
    const float* queue   = (const float*)d_in[4];
    float* ws  = (float*)d_ws;
    float* out = (float*)d_out;

    int*   sel     = (int*)(ws + WS_SEL);
    float* anorm   = ws + WS_ANORM;
    float* cnts    = ws + WS_CNTS;
    float* sums    = ws + WS_SUMS;
    float* negpart = ws + WS_NEGPART;
    float* arows   = ws + WS_AROWS;
    float* part    = ws + WS_PART;
    float* cntpart = ws + WS_CNTPART;

    k_select <<<26, 64, 0, stream>>>(labels, predict, prob, sel);
    k_partial<<<NBLK2, 256, 0, stream>>>(feats, labels, prob, part, cntpart);
    k_reduce <<<8, 256, 0, stream>>>(part, cntpart, sums, cnts);
    k_gather <<<TC * NV, 64, 0, stream>>>(feats, sel, arows, anorm);
    k_neg    <<<TC * NCHUNK, 256, 0, stream>>>(queue, arows, anorm, negpart);
    k_final  <<<1, 256, 0, stream>>>(arows, anorm, sums, cnts, negpart, out);
}

// Round 2
// 407.222 us; speedup vs baseline: 1.0220x; 1.0220x over previous
//
#include <hip/hip_runtime.h>

#define NUMC 14
#define FD 128
#define SPATIAL (16*128*128)      // 262144 per batch = 2^18
#define N_TOTAL (2*SPATIAL)       // 524288
#define NV 50
#define NH 25
#define TC 13
#define QLEN 4096
#define MCH 64                    // negatives per k_neg block
#define NCHUNK 32                 // 2048 / MCH
#define CHUNK 1024
#define NBLKP (N_TOTAL / CHUNK)   // 512 (k_prep blocks)
#define PXB 32768                 // pixels per k_sums block
#define CHB (SPATIAL / PXB)       // 8 chunks per channel-plane
#define NSUMBLK (256 * CHB)       // 2048 k_sums blocks
#define THRESH_F 0.3f

// ws offsets in 4-byte units
#define WS_SEL     0              // int[656]
#define WS_ANORM   656            // float[656]
#define WS_CNTS    1312           // float[16]
#define WS_SUMS    1328           // float[14*128]
#define WS_NEGPART 3120           // float[32*650]
#define WS_AROWS   23920          // float[650*128]
#define WS_PART    107120         // float[2048*14]
#define WS_CNTPART 135792         // float[512*16]
#define WS_LAB8    143984         // uchar[524288]

__global__ void k_select(const int* __restrict__ labels, const int* __restrict__ predict,
                         const float* __restrict__ prob, int* __restrict__ sel) {
    int cat = blockIdx.x;              // 0..25
    int c = 1 + (cat >> 1);
    bool hard = (cat & 1) == 0;
    int lane = threadIdx.x;            // 0..63
    int* slot = sel + (c - 1) * NV + (hard ? 0 : NH);
    int found = 0;
    for (int base = 0; base < N_TOTAL && found < NH; base += 64) {
        int n = base + lane;
        bool m = false;
        if (n < N_TOTAL) {
            int pr = predict[n];
            if (pr == c && prob[n] > THRESH_F) {
                int lb = labels[n];
                m = hard ? (lb != c) : (lb == c);
            }
        }
        unsigned long long mask = __ballot(m);
        int rank = __popcll(mask & ((1ull << lane) - 1ull));
        if (m && (found + rank) < NH) slot[found + rank] = n;
        found += __popcll(mask);
    }
    if (lane >= found && lane < NH) slot[lane] = N_TOTAL - 1;  // clamp semantics of OOB gather
}

// labels+prob -> 1-byte class id (0..13 valid, 15 invalid) + per-block class counts
__global__ __launch_bounds__(256) void k_prep(const int* __restrict__ labels,
        const float* __restrict__ prob, unsigned char* __restrict__ lab8,
        float* __restrict__ cntpart) {
    __shared__ float cnt_s[16];
    int tid = threadIdx.x;
    int base = blockIdx.x * CHUNK;
    if (tid < 16) cnt_s[tid] = 0.f;
    __syncthreads();
    int n = base + tid * 4;
    int4   lb = *(const int4*)(labels + n);
    float4 pv = *(const float4*)(prob + n);
    int l0 = pv.x > THRESH_F ? lb.x : 15;
    int l1 = pv.y > THRESH_F ? lb.y : 15;
    int l2 = pv.z > THRESH_F ? lb.z : 15;
    int l3 = pv.w > THRESH_F ? lb.w : 15;
    uchar4 o;
    o.x = (unsigned char)l0; o.y = (unsigned char)l1;
    o.z = (unsigned char)l2; o.w = (unsigned char)l3;
    *(uchar4*)(lab8 + n) = o;
    atomicAdd(&cnt_s[l0 & 15], 1.f);
    atomicAdd(&cnt_s[l1 & 15], 1.f);
    atomicAdd(&cnt_s[l2 & 15], 1.f);
    atomicAdd(&cnt_s[l3 & 15], 1.f);
    __syncthreads();
    if (tid < 16) cntpart[blockIdx.x * 16 + tid] = cnt_s[tid];
}

// per-class feature sums: each thread owns a private 17-float LDS row (no collisions)
__global__ __launch_bounds__(256) void k_sums(const float* __restrict__ feats,
        const unsigned char* __restrict__ lab8, float* __restrict__ part) {
    __shared__ float acc_s[256 * 17];   // 17.4 KB, stride 17 -> conflict-free banks
    int tid = threadIdx.x;
    int plane = blockIdx.x >> 3;        // 0..255 = b*128 + ch
    int chunk = blockIdx.x & (CHB - 1); // 0..7
    int b = plane >> 7;
    for (int i = tid; i < 256 * 17; i += 256) acc_s[i] = 0.f;
    __syncthreads();
    const float* fp = feats + (size_t)plane * SPATIAL + chunk * PXB;
    const unsigned char* lp = lab8 + (size_t)b * SPATIAL + chunk * PXB;
    int tid17 = tid * 17;
    for (int i = 0; i < PXB / 1024; ++i) {       // 32 iters
        int off = i * 1024 + tid * 4;
        float4 v = *(const float4*)(fp + off);
        uchar4 l = *(const uchar4*)(lp + off);
        atomicAdd(&acc_s[tid17 + l.x], v.x);     // ds_add_f32, fire-and-forget
        atomicAdd(&acc_s[tid17 + l.y], v.y);
        atomicAdd(&acc_s[tid17 + l.z], v.z);
        atomicAdd(&acc_s[tid17 + l.w], v.w);
    }
    __syncthreads();
    for (int s = 128; s >= 16; s >>= 1) {
        if (tid < s) {
            #pragma unroll
            for (int c = 0; c < NUMC; ++c) acc_s[tid * 17 + c] += acc_s[(tid + s) * 17 + c];
        }
        __syncthreads();
    }
    if (tid < NUMC) {
        float s = 0.f;
        #pragma unroll
        for (int r = 0; r < 16; ++r) s += acc_s[r * 17 + tid];
        part[blockIdx.x * NUMC + tid] = s;
    }
}

__global__ __launch_bounds__(256) void k_reduce(const float* __restrict__ part,
        const float* __restrict__ cntpart, float* __restrict__ sums, float* __restrict__ cnts) {
    int idx = blockIdx.x * 256 + threadIdx.x;
    if (idx < NUMC * FD) {
        int c = idx >> 7, ch = idx & 127;
        float s = 0.f;
        #pragma unroll
        for (int b = 0; b < 2; ++b)
            #pragma unroll
            for (int k = 0; k < CHB; ++k)
                s += part[(size_t)(((b << 7) + ch) * CHB + k) * NUMC + c];
        sums[idx] = s;   // layout [class][128]
    } else if (idx < NUMC * FD + 16) {
        int j = idx - NUMC * FD;
        float s = 0.f;
        for (int b = 0; b < NBLKP; ++b) s += cntpart[b * 16 + j];
        cnts[j] = s;
    }
}

__global__ __launch_bounds__(128) void k_gather(const float* __restrict__ feats,
        const int* __restrict__ sel, float* __restrict__ arows, float* __restrict__ anorm) {
    __shared__ float red[2];
    int r = blockIdx.x;          // 0..649
    int t = threadIdx.x;         // 0..127 = channel
    int n = sel[r];
    int b = n >> 18, sp = n & (SPATIAL - 1);
    float v = feats[((size_t)(b * FD + t)) * SPATIAL + sp];
    arows[r * FD + t] = v;
    float a = v * v;
    #pragma unroll
    for (int o = 32; o; o >>= 1) a += __shfl_xor(a, o);
    if ((t & 63) == 0) red[t >> 6] = a;
    __syncthreads();
    if (t == 0) anorm[r] = sqrtf(red[0] + red[1]);
}

__global__ __launch_bounds__(256) void k_neg(const float* __restrict__ queue,
        const float* __restrict__ arows, const float* __restrict__ anorm,
        float* __restrict__ negpart) {
    constexpr int NSTR = FD + 4;   // 132 floats: float4-aligned rows, banks spread
    __shared__ float a_s[NV * FD];
    __shared__ float n_s[MCH * NSTR];
    __shared__ float an_s[NV];
    int tid = threadIdx.x;
    int ci = blockIdx.x >> 5;      // 0..12
    int chunk = blockIdx.x & 31;   // 0..31
    const float* ap = arows + ci * (NV * FD);
    for (int i = tid; i < NV * FD / 4; i += 256) ((float4*)a_s)[i] = ((const float4*)ap)[i];
    if (tid < NV) an_s[tid] = anorm[ci * NV + tid];
    const float* qp = queue + ((size_t)(ci + 1) * QLEN + (QLEN / 2) + chunk * MCH) * (size_t)FD;
    for (int i = tid; i < MCH * FD / 4; i += 256) {
        int m = i / (FD / 4), k4 = i % (FD / 4);
        ((float4*)(n_s + m * NSTR))[k4] = ((const float4*)qp)[i];
    }
    __syncthreads();
    int lane = tid & 63, w = tid >> 6;
    float4 nr[FD / 4];
    const float4* nrow = (const float4*)(n_s + lane * NSTR);
    float sq = 0.f;
    #pragma unroll
    for (int k = 0; k < FD / 4; ++k) {
        nr[k] = nrow[k];
        sq += nr[k].x*nr[k].x + nr[k].y*nr[k].y + nr[k].z*nr[k].z + nr[k].w*nr[k].w;
    }
    float inn = 10.f / sqrtf(sq);   // 1/TEMP folded in
    float* np = negpart + chunk * (TC * NV) + ci * NV;
    for (int v = w; v < NV; v += 4) {
        const float4* a4 = (const float4*)(a_s + v * FD);  // wave-uniform -> LDS broadcast
        float dot = 0.f;
        #pragma unroll
        for (int k = 0; k < FD / 4; ++k) {
            float4 x = a4[k];
            dot += x.x*nr[k].x + x.y*nr[k].y + x.z*nr[k].z + x.w*nr[k].w;
        }
        float e = __expf(dot * inn / an_s[v]);
        #pragma unroll
        for (int o = 32; o; o >>= 1) e += __shfl_xor(e, o);
        if (lane == 0) np[v] = e;
    }
}

__global__ __launch_bounds__(256) void k_final(const float* __restrict__ arows,
        const float* __restrict__ anorm, const float* __restrict__ sums,
        const float* __restrict__ cnts, const float* __restrict__ negpart,
        float* __restrict__ out) {
    __shared__ float p_s[TC * FD];
    __shared__ float pn_s[TC];
    __shared__ float red[256];
    int tid = threadIdx.x;
    for (int i = tid; i < TC * FD; i += 256) {
        int c = i >> 7, k = i & 127;
        p_s[i] = sums[(c + 1) * FD + k] / cnts[c + 1];
    }
    __syncthreads();
    if (tid < TC) {
        float s = 0.f;
        for (int k = 0; k < FD; ++k) { float v = p_s[tid * FD + k]; s += v * v; }
        pn_s[tid] = sqrtf(s);
    }
    __syncthreads();
    float acc = 0.f;
    for (int r = tid; r < TC * NV; r += 256) {
        int c = r / NV;
        const float4* ar4 = (const float4*)(arows + r * FD);
        const float4* p4  = (const float4*)(p_s + c * FD);
        float dot = 0.f;
        #pragma unroll
        for (int k = 0; k < FD / 4; ++k) {
            float4 x = ar4[k], y = p4[k];
            dot += x.x*y.x + x.y*y.y + x.z*y.z + x.w*y.w;
        }
        float logit = dot / (anorm[r] * pn_s[c] * 0.1f);
        float ns = 0.f;
        for (int ch = 0; ch < NCHUNK; ++ch) ns += negpart[ch * (TC * NV) + r];
        acc += -logit + logf(__expf(logit) + ns);
    }
    red[tid] = acc;
    __syncthreads();
    for (int s = 128; s; s >>= 1) {
        if (tid < s) red[tid] += red[tid + s];
        __syncthreads();
    }
    if (tid == 0) out[0] = red[0] * (1.f / (TC * NV));
}

extern "C" void kernel_launch(void* const* d_in, const int* in_sizes, int n_in,
                              void* d_out, int out_size, void* d_ws, size_t ws_size,
                              hipStream_t stream) {
    (void)in_sizes; (void)n_in; (void)out_size; (void)ws_size;
    const float* feats   = (const float*)d_in[0];
    const int*   labels  = (const int*)d_in[1];
    const int*   predict = (const int*)d_in[2];
    const float* prob    = (const float*)d_in[3];
    const float* queue   = (const float*)d_in[4];
    float* ws  = (float*)d_ws;
    float* out = (float*)d_out;

    int*   sel     = (int*)(ws + WS_SEL);
    float* anorm   = ws + WS_ANORM;
    float* cnts    = ws + WS_CNTS;
    float* sums    = ws + WS_SUMS;
    float* negpart = ws + WS_NEGPART;
    float* arows   = ws + WS_AROWS;
    float* part    = ws + WS_PART;
    float* cntpart = ws + WS_CNTPART;
    unsigned char* lab8 = (unsigned char*)(ws + WS_LAB8);

    k_select <<<26, 64, 0, stream>>>(labels, predict, prob, sel);
    k_prep   <<<NBLKP, 256, 0, stream>>>(labels, prob, lab8, cntpart);
    k_sums   <<<NSUMBLK, 256, 0, stream>>>(feats, lab8, part);
    k_reduce <<<8, 256, 0, stream>>>(part, cntpart, sums, cnts);
    k_gather <<<TC * NV, 128, 0, stream>>>(feats, sel, arows, anorm);
    k_neg    <<<TC * NCHUNK, 256, 0, stream>>>(queue, arows, anorm, negpart);
    k_final  <<<1, 256, 0, stream>>>(arows, anorm, sums, cnts, negpart, out);
}

// Round 3
// 113.373 us; speedup vs baseline: 3.6708x; 3.5919x over previous
//
#include <hip/hip_runtime.h>

#define NUMC 14
#define FD 128
#define SPATIAL (16*128*128)      // 262144 per batch = 2^18
#define N_TOTAL (2*SPATIAL)       // 524288
#define NV 50
#define NH 25
#define TC 13
#define QLEN 4096
#define MCH 64                    // negatives per k_neg block
#define NCHUNK 32                 // 2048 / MCH
#define CHUNK 1024
#define NBLKP (N_TOTAL / CHUNK)   // 512 (k_prep blocks)
#define PXB 32768                 // pixels per k_sums block
#define CHB (SPATIAL / PXB)       // 8 chunks per channel-plane
#define NSUMBLK (256 * CHB)       // 2048 k_sums blocks
#define THRESH_F 0.3f
#define RSTR 35                   // per-thread LDS row stride (odd -> bank spread)

// ws offsets in 4-byte units
#define WS_SEL     0              // int[656]
#define WS_ANORM   656            // float[656]
#define WS_CNTS    1312           // float[16]
#define WS_SUMS    1328           // float[14*128]
#define WS_NEGPART 3120           // float[32*650]
#define WS_AROWS   23920          // float[650*128]
#define WS_PART    107120         // float[2048*14]
#define WS_CNTPART 135792         // int[512*16]
#define WS_LAB8    143984         // uchar[524288]

__global__ void k_select(const int* __restrict__ labels, const int* __restrict__ predict,
                         const float* __restrict__ prob, int* __restrict__ sel) {
    int cat = blockIdx.x;              // 0..25
    int c = 1 + (cat >> 1);
    bool hard = (cat & 1) == 0;
    int lane = threadIdx.x;            // 0..63
    int* slot = sel + (c - 1) * NV + (hard ? 0 : NH);
    int found = 0;
    for (int base = 0; base < N_TOTAL && found < NH; base += 64) {
        int n = base + lane;
        bool m = false;
        if (n < N_TOTAL) {
            int pr = predict[n];
            if (pr == c && prob[n] > THRESH_F) {
                int lb = labels[n];
                m = hard ? (lb != c) : (lb == c);
            }
        }
        unsigned long long mask = __ballot(m);
        int rank = __popcll(mask & ((1ull << lane) - 1ull));
        if (m && (found + rank) < NH) slot[found + rank] = n;
        found += __popcll(mask);
    }
    if (lane >= found && lane < NH) slot[lane] = N_TOTAL - 1;  // clamp semantics of OOB gather
}

// labels+prob -> 1-byte class id (0..13 valid, 15 invalid) + per-block class counts
// counts via ballot/popcount + INTEGER LDS atomics (native ds_add_u32, no CAS loop)
__global__ __launch_bounds__(256) void k_prep(const int* __restrict__ labels,
        const float* __restrict__ prob, unsigned char* __restrict__ lab8,
        int* __restrict__ cntpart) {
    __shared__ int cnt_s[16];
    int tid = threadIdx.x;
    int lane = tid & 63;
    int base = blockIdx.x * CHUNK;
    if (tid < 16) cnt_s[tid] = 0;
    __syncthreads();
    int n = base + tid * 4;
    int4   lb = *(const int4*)(labels + n);
    float4 pv = *(const float4*)(prob + n);
    int l0 = pv.x > THRESH_F ? (lb.x & 15) : 15;
    int l1 = pv.y > THRESH_F ? (lb.y & 15) : 15;
    int l2 = pv.z > THRESH_F ? (lb.z & 15) : 15;
    int l3 = pv.w > THRESH_F ? (lb.w & 15) : 15;
    uchar4 o;
    o.x = (unsigned char)l0; o.y = (unsigned char)l1;
    o.z = (unsigned char)l2; o.w = (unsigned char)l3;
    *(uchar4*)(lab8 + n) = o;
    #pragma unroll
    for (int c = 0; c < 16; ++c) {
        if (c == 14) continue;   // class 14 never occurs
        int cnt = __popcll(__ballot(l0 == c)) + __popcll(__ballot(l1 == c))
                + __popcll(__ballot(l2 == c)) + __popcll(__ballot(l3 == c));
        if (lane == 0 && cnt) atomicAdd(&cnt_s[c], cnt);
    }
    __syncthreads();
    if (tid < 16) cntpart[blockIdx.x * 16 + tid] = cnt_s[tid];
}

// per-class feature sums: each thread owns TWO provably-disjoint private LDS
// sub-rows (plain +=, NO atomics -> no CAS loops, two independent RMW chains)
__global__ __launch_bounds__(256) void k_sums(const float* __restrict__ feats,
        const unsigned char* __restrict__ lab8, float* __restrict__ part) {
    __shared__ float acc_s[256 * RSTR];   // 35.8 KB
    int tid = threadIdx.x;
    int plane = blockIdx.x >> 3;        // 0..255 = b*128 + ch
    int chunk = blockIdx.x & (CHB - 1); // 0..7
    int b = plane >> 7;
    for (int i = tid; i < 256 * RSTR; i += 256) acc_s[i] = 0.f;
    __syncthreads();
    const float* fp = feats + (size_t)plane * SPATIAL + chunk * PXB;
    const unsigned char* lp = lab8 + (size_t)b * SPATIAL + chunk * PXB;
    int r0 = tid * RSTR;       // sub-row 0: slots [r0, r0+15]
    int r1 = r0 + 18;          // sub-row 1: slots [r0+18, r0+33]  (disjoint)
    float4 v = *(const float4*)(fp + tid * 4);
    uchar4 l = *(const uchar4*)(lp + tid * 4);
    for (int i = 0; i < PXB / 1024; ++i) {       // 32 iters, next-iter prefetch
        int ip = (i + 1 < PXB / 1024) ? i + 1 : i;
        int offn = ip * 1024 + tid * 4;
        float4 vn = *(const float4*)(fp + offn);
        uchar4 ln = *(const uchar4*)(lp + offn);
        acc_s[r0 + (l.x & 15)] += v.x;
        acc_s[r1 + (l.y & 15)] += v.y;
        acc_s[r0 + (l.z & 15)] += v.z;
        acc_s[r1 + (l.w & 15)] += v.w;
        v = vn; l = ln;
    }
    __syncthreads();
    // fold sub-row 1 into sub-row 0
    #pragma unroll
    for (int c = 0; c < NUMC; ++c) acc_s[r0 + c] += acc_s[r1 + c];
    __syncthreads();
    // tree over 256 rows
    for (int s = 128; s >= 16; s >>= 1) {
        if (tid < s) {
            #pragma unroll
            for (int c = 0; c < NUMC; ++c)
                acc_s[tid * RSTR + c] += acc_s[(tid + s) * RSTR + c];
        }
        __syncthreads();
    }
    if (tid < NUMC) {
        float s = 0.f;
        #pragma unroll
        for (int r = 0; r < 16; ++r) s += acc_s[r * RSTR + tid];
        part[blockIdx.x * NUMC + tid] = s;
    }
}

__global__ __launch_bounds__(256) void k_reduce(const float* __restrict__ part,
        const int* __restrict__ cntpart, float* __restrict__ sums, float* __restrict__ cnts) {
    int idx = blockIdx.x * 256 + threadIdx.x;
    if (idx < NUMC * FD) {
        int c = idx >> 7, ch = idx & 127;
        float s = 0.f;
        #pragma unroll
        for (int b = 0; b < 2; ++b)
            #pragma unroll
            for (int k = 0; k < CHB; ++k)
                s += part[(size_t)(((b << 7) + ch) * CHB + k) * NUMC + c];
        sums[idx] = s;   // layout [class][128]
    } else if (idx < NUMC * FD + 16) {
        int j = idx - NUMC * FD;
        int s = 0;
        for (int b = 0; b < NBLKP; ++b) s += cntpart[b * 16 + j];
        cnts[j] = (float)s;
    }
}

__global__ __launch_bounds__(128) void k_gather(const float* __restrict__ feats,
        const int* __restrict__ sel, float* __restrict__ arows, float* __restrict__ anorm) {
    __shared__ float red[2];
    int r = blockIdx.x;          // 0..649
    int t = threadIdx.x;         // 0..127 = channel
    int n = sel[r];
    int b = n >> 18, sp = n & (SPATIAL - 1);
    float v = feats[((size_t)(b * FD + t)) * SPATIAL + sp];
    arows[r * FD + t] = v;
    float a = v * v;
    #pragma unroll
    for (int o = 32; o; o >>= 1) a += __shfl_xor(a, o);
    if ((t & 63) == 0) red[t >> 6] = a;
    __syncthreads();
    if (t == 0) anorm[r] = sqrtf(red[0] + red[1]);
}

__global__ __launch_bounds__(256) void k_neg(const float* __restrict__ queue,
        const float* __restrict__ arows, const float* __restrict__ anorm,
        float* __restrict__ negpart) {
    constexpr int NSTR = FD + 4;   // 132 floats: float4-aligned rows, banks spread
    __shared__ float a_s[NV * FD];
    __shared__ float n_s[MCH * NSTR];
    __shared__ float an_s[NV];
    int tid = threadIdx.x;
    int ci = blockIdx.x >> 5;      // 0..12
    int chunk = blockIdx.x & 31;   // 0..31
    const float* ap = arows + ci * (NV * FD);
    for (int i = tid; i < NV * FD / 4; i += 256) ((float4*)a_s)[i] = ((const float4*)ap)[i];
    if (tid < NV) an_s[tid] = anorm[ci * NV + tid];
    const float* qp = queue + ((size_t)(ci + 1) * QLEN + (QLEN / 2) + chunk * MCH) * (size_t)FD;
    for (int i = tid; i < MCH * FD / 4; i += 256) {
        int m = i / (FD / 4), k4 = i % (FD / 4);
        ((float4*)(n_s + m * NSTR))[k4] = ((const float4*)qp)[i];
    }
    __syncthreads();
    int lane = tid & 63, w = tid >> 6;
    float4 nr[FD / 4];
    const float4* nrow = (const float4*)(n_s + lane * NSTR);
    float sq = 0.f;
    #pragma unroll
    for (int k = 0; k < FD / 4; ++k) {
        nr[k] = nrow[k];
        sq += nr[k].x*nr[k].x + nr[k].y*nr[k].y + nr[k].z*nr[k].z + nr[k].w*nr[k].w;
    }
    float inn = 10.f / sqrtf(sq);   // 1/TEMP folded in
    float* np = negpart + chunk * (TC * NV) + ci * NV;
    for (int v = w; v < NV; v += 4) {
        const float4* a4 = (const float4*)(a_s + v * FD);  // wave-uniform -> LDS broadcast
        float dot = 0.f;
        #pragma unroll
        for (int k = 0; k < FD / 4; ++k) {
            float4 x = a4[k];
            dot += x.x*nr[k].x + x.y*nr[k].y + x.z*nr[k].z + x.w*nr[k].w;
        }
        float e = __expf(dot * inn / an_s[v]);
        #pragma unroll
        for (int o = 32; o; o >>= 1) e += __shfl_xor(e, o);
        if (lane == 0) np[v] = e;
    }
}

__global__ __launch_bounds__(256) void k_final(const float* __restrict__ arows,
        const float* __restrict__ anorm, const float* __restrict__ sums,
        const float* __restrict__ cnts, const float* __restrict__ negpart,
        float* __restrict__ out) {
    __shared__ float p_s[TC * FD];
    __shared__ float pn_s[TC];
    __shared__ float red[256];
    int tid = threadIdx.x;
    for (int i = tid; i < TC * FD; i += 256) {
        int c = i >> 7, k = i & 127;
        p_s[i] = sums[(c + 1) * FD + k] / cnts[c + 1];
    }
    __syncthreads();
    if (tid < TC) {
        float s = 0.f;
        for (int k = 0; k < FD; ++k) { float v = p_s[tid * FD + k]; s += v * v; }
        pn_s[tid] = sqrtf(s);
    }
    __syncthreads();
    float acc = 0.f;
    for (int r = tid; r < TC * NV; r += 256) {
        int c = r / NV;
        const float4* ar4 = (const float4*)(arows + r * FD);
        const float4* p4  = (const float4*)(p_s + c * FD);
        float dot = 0.f;
        #pragma unroll
        for (int k = 0; k < FD / 4; ++k) {
            float4 x = ar4[k], y = p4[k];
            dot += x.x*y.x + x.y*y.y + x.z*y.z + x.w*y.w;
        }
        float logit = dot / (anorm[r] * pn_s[c] * 0.1f);
        float ns = 0.f;
        for (int ch = 0; ch < NCHUNK; ++ch) ns += negpart[ch * (TC * NV) + r];
        acc += -logit + logf(__expf(logit) + ns);
    }
    red[tid] = acc;
    __syncthreads();
    for (int s = 128; s; s >>= 1) {
        if (tid < s) red[tid] += red[tid + s];
        __syncthreads();
    }
    if (tid == 0) out[0] = red[0] * (1.f / (TC * NV));
}

extern "C" void kernel_launch(void* const* d_in, const int* in_sizes, int n_in,
                              void* d_out, int out_size, void* d_ws, size_t ws_size,
                              hipStream_t stream) {
    (void)in_sizes; (void)n_in; (void)out_size; (void)ws_size;
    const float* feats   = (const float*)d_in[0];
    const int*   labels  = (const int*)d_in[1];
    const int*   predict = (const int*)d_in[2];
    const float* prob    = (const float*)d_in[3];
    const float* queue   = (const float*)d_in[4];
    float* ws  = (float*)d_ws;
    float* out = (float*)d_out;

    int*   sel     = (int*)(ws + WS_SEL);
    float* anorm   = ws + WS_ANORM;
    float* cnts    = ws + WS_CNTS;
    float* sums    = ws + WS_SUMS;
    float* negpart = ws + WS_NEGPART;
    float* arows   = ws + WS_AROWS;
    float* part    = ws + WS_PART;
    int*   cntpart = (int*)(ws + WS_CNTPART);
    unsigned char* lab8 = (unsigned char*)(ws + WS_LAB8);

    k_select <<<26, 64, 0, stream>>>(labels, predict, prob, sel);
    k_prep   <<<NBLKP, 256, 0, stream>>>(labels, prob, lab8, cntpart);
    k_sums   <<<NSUMBLK, 256, 0, stream>>>(feats, lab8, part);
    k_reduce <<<8, 256, 0, stream>>>(part, cntpart, sums, cnts);
    k_gather <<<TC * NV, 128, 0, stream>>>(feats, sel, arows, anorm);
    k_neg    <<<TC * NCHUNK, 256, 0, stream>>>(queue, arows, anorm, negpart);
    k_final  <<<1, 256, 0, stream>>>(arows, anorm, sums, cnts, negpart, out);
}